// Round 5
// baseline (269.767 us; speedup 1.0000x reference)
//
#include <hip/hip_runtime.h>

// AirFitMultiHeadDNN — R5: algebraic folding.
// R4 post-mortem: VALU inst/wave ~2.2k vs 650 ideal; suspect the ~430
// wave-uniform weight scalars per template case (W1 slice = 320) churn
// through s_load/SGPR with just-in-time reloads + lgkmcnt stalls.
// Fold the affine prefix offline (setup kernel -> d_ws):
//   M[h] = Wf @ W1[h][3:8,:]                   (20 x 3 x 10)
//   T[h][idx][o] = emb[idx]·W1[h][0:3,o] + bf·W1[h][3:8,o] + b1[h][o]
//                                              (20 x 13 x 10; only 13 idx!)
// Then per head: h1 = leaky(T[h][e] + f·M[h]); s = softplus(h1·W2 + b2);
// out = sum s·Wo + bo.  Per-head cost: 30 FMA + 3 LDS reads (T row)
// vs 95 FMA + 320 W1 s_loads before.
// Structure kept from R4 (it worked): 320-thread blocks = 5 waves x 64
// items, wave j handles heads [4j,4j+4), compile-time-J template via
// readfirstlane switch -> M/W2/b2/Wo on the s_load path.
// T in LDS, rows strided 12 floats (48 B): bank-start period 8 over idx,
// <=2-way aliasing (free on gfx950).

#define HH   20
#define NEX  13
#define TST  12                 // T row stride in floats (16B-aligned reads)
#define WS_M 0                  // M at d_ws[0..600)
#define WS_T 640                // T at d_ws[640..640+20*13*12)

__device__ __forceinline__ float softplus_fast(float x) {
    return fmaxf(x, 0.0f) + __logf(1.0f + __expf(-fabsf(x)));
}

// ---------------- setup: fold weights into M and T ----------------
__global__ void airfit_setup(const float* __restrict__ emb,
                             const float* __restrict__ Wf,
                             const float* __restrict__ bf,
                             const float* __restrict__ W1,
                             const float* __restrict__ b1,
                             float* __restrict__ ws)
{
    int t = blockIdx.x * 256 + threadIdx.x;
    if (t < HH * 3 * 10) {                       // M[h][c][o]
        int h = t / 30, c = (t / 10) % 3, o = t % 10;
        float a = 0.0f;
        for (int q = 0; q < 5; ++q)
            a += Wf[c * 5 + q] * W1[(h * 8 + 3 + q) * 10 + o];
        ws[WS_M + (h * 3 + c) * 10 + o] = a;
    }
    if (t < HH * NEX * 10) {                     // T[h][idx][o]
        int h = t / (NEX * 10), idx = (t / 10) % NEX, o = t % 10;
        float a = b1[h * 10 + o];
        for (int i = 0; i < 3; ++i)
            a += emb[idx * 3 + i] * W1[(h * 8 + i) * 10 + o];
        for (int q = 0; q < 5; ++q)
            a += bf[q] * W1[(h * 8 + 3 + q) * 10 + o];
        ws[WS_T + (h * NEX + idx) * TST + o] = a;
    }
}

// ---------------- main ----------------
template<int J>
__device__ __forceinline__ float head_group(
    int4 iv, float4 fa, float4 fb, float4 fc,
    const float* __restrict__ s_T,
    const float* __restrict__ M,     // d_ws + WS_M, uniform idx -> s_load
    const float* __restrict__ W2, const float* __restrict__ b2,
    const float* __restrict__ Wo)
{
    int   ii[4]  = { iv.x, iv.y, iv.z, iv.w };
    float ff[12] = { fa.x, fa.y, fa.z, fa.w,
                     fb.x, fb.y, fb.z, fb.w,
                     fc.x, fc.y, fc.z, fc.w };
    float partial = 0.0f;

#pragma unroll
    for (int t = 0; t < 4; ++t) {
        const int h = 4 * J + t;                 // compile-time constant
        const float* Trow = s_T + (h * NEX + ii[t]) * TST;
        float4 t0 = *reinterpret_cast<const float4*>(Trow);      // o0..3
        float4 t1 = *reinterpret_cast<const float4*>(Trow + 4);  // o4..7
        float2 t2 = *reinterpret_cast<const float2*>(Trow + 8);  // o8..9
        float pre[10] = { t0.x, t0.y, t0.z, t0.w,
                          t1.x, t1.y, t1.z, t1.w, t2.x, t2.y };

        float g0 = ff[3 * t + 0], g1 = ff[3 * t + 1], g2 = ff[3 * t + 2];
        float hacc = b2[h];
#pragma unroll
        for (int o = 0; o < 10; ++o) {
            float a = pre[o];
            a = fmaf(g0, M[(h * 3 + 0) * 10 + o], a);
            a = fmaf(g1, M[(h * 3 + 1) * 10 + o], a);
            a = fmaf(g2, M[(h * 3 + 2) * 10 + o], a);
            a = fmaxf(a, 0.01f * a);             // leaky_relu
            hacc = fmaf(a, W2[h * 10 + o], hacc);
        }
        partial = fmaf(softplus_fast(hacc), Wo[h], partial);
    }
    return partial;
}

__global__ __launch_bounds__(320, 6) void airfit_kernel(
    const int*   __restrict__ e,   const float* __restrict__ f,
    const float* __restrict__ ws,  const float* __restrict__ W2,
    const float* __restrict__ b2,  const float* __restrict__ Wo,
    const float* __restrict__ bo,  float* __restrict__ out, int B)
{
    __shared__ float s_T[HH * NEX * TST];        // 3120 floats = 12.5 KB
    __shared__ float s_part[5][64];

    // stage folded T table into LDS (global copy is L2/L3-resident)
    for (int t = threadIdx.x; t < HH * NEX * TST; t += 320)
        s_T[t] = ws[WS_T + t];
    __syncthreads();

    const int i    = threadIdx.x & 63;           // item within block
    const int jj   = threadIdx.x >> 6;           // head group (wave-uniform)
    const int item = blockIdx.x * 64 + i;
    const float* M = ws + WS_M;

    if (item < B) {
        int4 iv = *(reinterpret_cast<const int4*>(e + (size_t)item * HH) + jj);
        const float4* fp =
            reinterpret_cast<const float4*>(f + (size_t)item * (HH * 3)) + 3 * jj;
        float4 fa = fp[0], fb = fp[1], fc = fp[2];

        const int j = __builtin_amdgcn_readfirstlane(jj);
        float partial;
        switch (j) {
        case 0:  partial = head_group<0>(iv, fa, fb, fc, s_T, M, W2, b2, Wo); break;
        case 1:  partial = head_group<1>(iv, fa, fb, fc, s_T, M, W2, b2, Wo); break;
        case 2:  partial = head_group<2>(iv, fa, fb, fc, s_T, M, W2, b2, Wo); break;
        case 3:  partial = head_group<3>(iv, fa, fb, fc, s_T, M, W2, b2, Wo); break;
        default: partial = head_group<4>(iv, fa, fb, fc, s_T, M, W2, b2, Wo); break;
        }
        s_part[jj][i] = partial;
    }
    __syncthreads();

    if (jj == 0 && item < B) {
        float r = bo[0] + s_part[0][i] + s_part[1][i] + s_part[2][i]
                        + s_part[3][i] + s_part[4][i];
        out[item] = r;
    }
}

extern "C" void kernel_launch(void* const* d_in, const int* in_sizes, int n_in,
                              void* d_out, int out_size, void* d_ws, size_t ws_size,
                              hipStream_t stream) {
    const int*   e   = (const int*)  d_in[0];
    const float* f   = (const float*)d_in[1];
    const float* emb = (const float*)d_in[2];
    const float* Wf  = (const float*)d_in[3];
    const float* bf  = (const float*)d_in[4];
    const float* W1  = (const float*)d_in[5];
    const float* b1  = (const float*)d_in[6];
    const float* W2  = (const float*)d_in[7];
    const float* b2  = (const float*)d_in[8];
    const float* Wo  = (const float*)d_in[9];
    const float* bo  = (const float*)d_in[10];
    float* out = (float*)d_out;
    float* ws  = (float*)d_ws;

    int B = in_sizes[0] / HH;                    // e is (B, 20)

    airfit_setup<<<11, 256, 0, stream>>>(emb, Wf, bf, W1, b1, ws);

    int blocks = (B + 63) / 64;                  // 64 items / 320-thread block
    airfit_kernel<<<blocks, 320, 0, stream>>>(e, f, ws, W2, b2, Wo, bo, out, B);
}